// Round 1
// baseline (536.331 us; speedup 1.0000x reference)
//
#include <hip/hip_runtime.h>

// Problem constants (B=1)
constexpr int Cc = 32;
constexpr int Dd = 48;
constexpr int Hh = 96;
constexpr int Ww = 192;
constexpr int TW = 32;           // W-kernel tile width
constexpr int NT = Ww / TW;      // 6 tiles
constexpr float NEGBIG = -3.402823466e+38f;

// ---- DPP helpers -----------------------------------------------------------
template <int CTRL, int RM>
__device__ __forceinline__ float dppmov(float v) {
    int i = __builtin_bit_cast(int, v);
    int r = __builtin_amdgcn_update_dpp(i, i, CTRL, RM, 0xF, false); // invalid lanes keep old(=v)
    return __builtin_bit_cast(float, r);
}

// Max over all 64 lanes (lanes 48..63 must hold -inf-ish identity), broadcast to all lanes.
__device__ __forceinline__ float wave_max_f32(float v) {
    v = fmaxf(v, dppmov<0x111, 0xF>(v));   // row_shr:1
    v = fmaxf(v, dppmov<0x112, 0xF>(v));   // row_shr:2
    v = fmaxf(v, dppmov<0x114, 0xF>(v));   // row_shr:4
    v = fmaxf(v, dppmov<0x118, 0xF>(v));   // row_shr:8  -> lane15 of each row has row max
    v = fmaxf(v, dppmov<0x142, 0xA>(v));   // row_bcast:15 into rows 1,3 -> lane31 = max(0..31), lane63 = max(32..47)
    v = fmaxf(v, dppmov<0x143, 0xC>(v));   // row_bcast:31 into rows 2,3 -> lane63 = global max
    int m = __builtin_amdgcn_readlane(__builtin_bit_cast(int, v), 63);
    return __builtin_bit_cast(float, m);
}

// One SGA step. A holds previous aggregated values per lane(=d); lanes>=48 hold NEGBIG.
__device__ __forceinline__ float sga_step(float A, float cs, float g0v, float g1v, float g2v,
                                          float g3v, float g4v, int lane, bool first) {
    float dm1 = dppmov<0x138, 0xF>(A);             // wave_shr:1, lane0 keeps own (d-1 clamp)
    float dp1 = dppmov<0x130, 0xF>(A);             // wave_shl:1
    dp1 = (lane == Dd - 1) ? A : dp1;              // d+1 clamp at d=47
    float mx = wave_max_f32(A);
    float r = g0v * cs + g1v * A + g2v * dm1 + g3v * dp1 + g4v * mx;
    r = first ? cs : r;
    return (lane < Dd) ? r : NEGBIG;
}

// ---- W-direction scan (axis=4). One wave per (c,h) row. --------------------
template <bool REV, bool COMB>
__global__ __launch_bounds__(64) void sga_w(const float* __restrict__ x,
                                            const float* __restrict__ g,
                                            float* __restrict__ out) {
    __shared__ float xs[2][Dd][TW + 1];
    __shared__ float os[Dd][TW + 1];

    const int bid = blockIdx.x;
    const int c = bid / Hh;
    const int h = bid - c * Hh;
    const int lane = threadIdx.x;
    const size_t HW = (size_t)Hh * Ww;

    const float* xrow = x + (size_t)c * Dd * HW + (size_t)h * Ww;
    const float* grow = g + (size_t)c * 5 * HW + (size_t)h * Ww;
    float* orow = out + (size_t)c * Dd * HW + (size_t)h * Ww;

    const int rsub = lane >> 3;        // 0..7
    const int cq = (lane & 7) * 4;     // 0,4,..,28
    const int dl = (lane < Dd) ? lane : (Dd - 1);

    float4 pre[6];

    // prologue: load first scan tile into xs[0]
    {
        const int t = REV ? (NT - 1) : 0;
        const int w0 = t * TW;
#pragma unroll
        for (int i = 0; i < 6; ++i) {
            const int dd = i * 8 + rsub;
            pre[i] = *reinterpret_cast<const float4*>(xrow + (size_t)dd * HW + (w0 + cq));
        }
#pragma unroll
        for (int i = 0; i < 6; ++i) {
            const int dd = i * 8 + rsub;
            xs[0][dd][cq + 0] = pre[i].x;
            xs[0][dd][cq + 1] = pre[i].y;
            xs[0][dd][cq + 2] = pre[i].z;
            xs[0][dd][cq + 3] = pre[i].w;
        }
    }
    __syncthreads();

    float A = NEGBIG;

    for (int tt = 0; tt < NT; ++tt) {
        const int t = REV ? (NT - 1 - tt) : tt;
        const int w0 = t * TW;
        const int buf = tt & 1;

        // issue next-tile x loads into registers (hidden under the 32-step chain)
        if (tt + 1 < NT) {
            const int tn = REV ? (NT - 2 - tt) : (tt + 1);
            const int wn = tn * TW;
#pragma unroll
            for (int i = 0; i < 6; ++i) {
                const int dd = i * 8 + rsub;
                pre[i] = *reinterpret_cast<const float4*>(xrow + (size_t)dd * HW + (wn + cq));
            }
        }
        // prefetch the out tile we will combine into at flush
        float4 opre[6];
        if (COMB) {
#pragma unroll
            for (int i = 0; i < 6; ++i) {
                const int dd = i * 8 + rsub;
                opre[i] = *reinterpret_cast<const float4*>(orow + (size_t)dd * HW + (w0 + cq));
            }
        }

        // 32 recurrence steps
#pragma unroll 4
        for (int wk = 0; wk < TW; ++wk) {
            const int col = REV ? (TW - 1 - wk) : wk;
            const int w = w0 + col;
            const float cs = xs[buf][dl][col];
            const float g0v = grow[0 * HW + w];
            const float g1v = grow[1 * HW + w];
            const float g2v = grow[2 * HW + w];
            const float g3v = grow[3 * HW + w];
            const float g4v = grow[4 * HW + w];
            A = sga_step(A, cs, g0v, g1v, g2v, g3v, g4v, lane, (tt == 0 && wk == 0));
            if (lane < Dd) os[lane][col] = A;
        }

        // commit prefetched next tile into the other xs buffer
        if (tt + 1 < NT) {
#pragma unroll
            for (int i = 0; i < 6; ++i) {
                const int dd = i * 8 + rsub;
                xs[buf ^ 1][dd][cq + 0] = pre[i].x;
                xs[buf ^ 1][dd][cq + 1] = pre[i].y;
                xs[buf ^ 1][dd][cq + 2] = pre[i].z;
                xs[buf ^ 1][dd][cq + 3] = pre[i].w;
            }
        }

        // flush os tile to out (coalesced), combining if requested
#pragma unroll
        for (int i = 0; i < 6; ++i) {
            const int dd = i * 8 + rsub;
            float4 v;
            v.x = os[dd][cq + 0];
            v.y = os[dd][cq + 1];
            v.z = os[dd][cq + 2];
            v.w = os[dd][cq + 3];
            if (COMB) {
                v.x = fmaxf(v.x, opre[i].x);
                v.y = fmaxf(v.y, opre[i].y);
                v.z = fmaxf(v.z, opre[i].z);
                v.w = fmaxf(v.w, opre[i].w);
            }
            *reinterpret_cast<float4*>(orow + (size_t)dd * HW + (w0 + cq)) = v;
        }
        __syncthreads();
    }
}

// ---- H-direction scan (axis=3). 8 waves per block, wave = one w column. ----
template <bool REV, bool COMB>
__global__ __launch_bounds__(512) void sga_h(const float* __restrict__ x,
                                             const float* __restrict__ g,
                                             float* __restrict__ out) {
    constexpr int WT = 8;
    constexpr int NWT = Ww / WT;   // 24

    __shared__ float xs[2][Dd][WT + 1];
    __shared__ float os[2][Dd][WT + 1];

    const int c = blockIdx.x / NWT;
    const int wt = blockIdx.x - c * NWT;
    const int w0 = wt * WT;
    const int tid = threadIdx.x;
    const int lane = tid & 63;
    const int wave = tid >> 6;            // 0..7 -> column
    const int wcol = w0 + wave;
    const size_t HW = (size_t)Hh * Ww;

    const float* xbase = x + (size_t)c * Dd * HW;
    const float* gbase = g + (size_t)c * 5 * HW;
    float* obase = out + (size_t)c * Dd * HW;

    const int sd = tid >> 3;              // staging row (d), valid for tid<384
    const int sw = tid & 7;               // staging col
    const bool stager = tid < Dd * WT;    // 384 threads stage/flush
    const int dl = (lane < Dd) ? lane : (Dd - 1);

    {
        const int h0 = REV ? (Hh - 1) : 0;
        if (stager) xs[0][sd][sw] = xbase[(size_t)sd * HW + (size_t)h0 * Ww + (w0 + sw)];
    }
    __syncthreads();

    float A = NEGBIG;
    float oprev = 0.f;   // prefetched out value for next flush

    for (int p = 0; p < Hh; ++p) {
        const int h = REV ? (Hh - 1 - p) : p;
        const int buf = p & 1;

        // issue next x row load
        float xnext = 0.f;
        const bool hasnext = (p + 1 < Hh);
        if (stager && hasnext) {
            const int hn = REV ? (Hh - 2 - p) : (p + 1);
            xnext = xbase[(size_t)sd * HW + (size_t)hn * Ww + (w0 + sw)];
        }
        // prefetch out for THIS h (consumed by next iteration's flush)
        float onow = 0.f;
        if (COMB && stager) onow = obase[(size_t)sd * HW + (size_t)h * Ww + (w0 + sw)];

        // flush previous step's os
        if (p > 0 && stager) {
            const int hp = REV ? (Hh - p) : (p - 1);
            float v = os[buf ^ 1][sd][sw];
            if (COMB) v = fmaxf(v, oprev);
            obase[(size_t)sd * HW + (size_t)hp * Ww + (w0 + sw)] = v;
        }
        oprev = onow;

        // compute this step for my column
        const float cs = xs[buf][dl][wave];
        const float g0v = gbase[0 * HW + (size_t)h * Ww + wcol];
        const float g1v = gbase[1 * HW + (size_t)h * Ww + wcol];
        const float g2v = gbase[2 * HW + (size_t)h * Ww + wcol];
        const float g3v = gbase[3 * HW + (size_t)h * Ww + wcol];
        const float g4v = gbase[4 * HW + (size_t)h * Ww + wcol];
        A = sga_step(A, cs, g0v, g1v, g2v, g3v, g4v, lane, (p == 0));
        if (lane < Dd) os[buf][lane][wave] = A;

        // commit next x row
        if (stager && hasnext) xs[buf ^ 1][sd][sw] = xnext;

        __syncthreads();
    }

    // final flush (last step's os)
    if (stager) {
        const int hl = REV ? 0 : (Hh - 1);
        float v = os[(Hh - 1) & 1][sd][sw];
        if (COMB) v = fmaxf(v, oprev);
        obase[(size_t)sd * HW + (size_t)hl * Ww + (w0 + sw)] = v;
    }
}

extern "C" void kernel_launch(void* const* d_in, const int* in_sizes, int n_in,
                              void* d_out, int out_size, void* d_ws, size_t ws_size,
                              hipStream_t stream) {
    const float* x  = (const float*)d_in[0];
    const float* g0 = (const float*)d_in[1];
    const float* g1 = (const float*)d_in[2];
    const float* g2 = (const float*)d_in[3];
    const float* g3 = (const float*)d_in[4];
    float* out = (float*)d_out;

    // a0: W forward (writes out), a1: W backward (max-combine),
    // a2: H forward (max-combine), a3: H backward (max-combine)
    sga_w<false, false><<<Cc * Hh, 64, 0, stream>>>(x, g0, out);
    sga_w<true,  true ><<<Cc * Hh, 64, 0, stream>>>(x, g1, out);
    sga_h<false, true ><<<Cc * (Ww / 8), 512, 0, stream>>>(x, g2, out);
    sga_h<true,  true ><<<Cc * (Ww / 8), 512, 0, stream>>>(x, g3, out);
}

// Round 2
// 335.691 us; speedup vs baseline: 1.5977x; 1.5977x over previous
//
#include <hip/hip_runtime.h>

// Problem constants (B=1)
constexpr int Cc = 32;
constexpr int Dd = 48;
constexpr int Hh = 96;
constexpr int Ww = 192;
constexpr int TW = 32;           // W-kernel tile width
constexpr int NT = Ww / TW;      // 6 tiles
constexpr float NEGBIG = -3.402823466e+38f;

// ---- DPP helpers -----------------------------------------------------------
template <int CTRL, int RM>
__device__ __forceinline__ float dppmov(float v) {
    int i = __builtin_bit_cast(int, v);
    int r = __builtin_amdgcn_update_dpp(i, i, CTRL, RM, 0xF, false); // invalid lanes keep old(=v)
    return __builtin_bit_cast(float, r);
}

__device__ __forceinline__ float rdlane(float v, int idx) {
    int r = __builtin_amdgcn_readlane(__builtin_bit_cast(int, v), idx);
    return __builtin_bit_cast(float, r);
}

// Max over all 64 lanes (lanes 48..63 must hold -inf identity), broadcast.
__device__ __forceinline__ float wave_max_f32(float v) {
    v = fmaxf(v, dppmov<0x111, 0xF>(v));   // row_shr:1
    v = fmaxf(v, dppmov<0x112, 0xF>(v));   // row_shr:2
    v = fmaxf(v, dppmov<0x114, 0xF>(v));   // row_shr:4
    v = fmaxf(v, dppmov<0x118, 0xF>(v));   // row_shr:8
    v = fmaxf(v, dppmov<0x142, 0xA>(v));   // row_bcast:15
    v = fmaxf(v, dppmov<0x143, 0xC>(v));   // row_bcast:31 -> lane63 = global max
    int m = __builtin_amdgcn_readlane(__builtin_bit_cast(int, v), 63);
    return __builtin_bit_cast(float, m);
}

// One SGA step. lane = d; lanes >= 48 hold NEGBIG.
__device__ __forceinline__ float sga_step(float A, float cs, float g0v, float g1v, float g2v,
                                          float g3v, float g4v, int lane, bool first) {
    float dm1 = dppmov<0x138, 0xF>(A);             // wave_shr:1, lane0 keeps own (d-1 clamp)
    float dp1 = dppmov<0x130, 0xF>(A);             // wave_shl:1
    dp1 = (lane == Dd - 1) ? A : dp1;              // d+1 clamp at d=47
    float mx = wave_max_f32(A);
    float r = g0v * cs + g1v * A + g2v * dm1 + g3v * dp1 + g4v * mx;
    r = first ? cs : r;
    return (lane < Dd) ? r : NEGBIG;
}

// ---- W-direction scan (axis=4). One wave per (c,h) row. --------------------
// Single-wave block: no barriers needed. g per tile held in registers
// (lane-indexed by column), read per step via v_readlane (SGPR index).
template <bool REV, bool COMB>
__global__ __launch_bounds__(64) void sga_w(const float* __restrict__ x,
                                            const float* __restrict__ g,
                                            float* __restrict__ out) {
    __shared__ float xs[Dd][TW + 1];
    __shared__ float os[Dd][TW + 1];

    const int bid = blockIdx.x;
    const int c = bid / Hh;
    const int h = bid - c * Hh;
    const int lane = threadIdx.x;
    const size_t HW = (size_t)Hh * Ww;

    const float* xrow = x + (size_t)c * Dd * HW + (size_t)h * Ww;
    const float* grow = g + (size_t)c * 5 * HW + (size_t)h * Ww;
    float* orow = out + (size_t)c * Dd * HW + (size_t)h * Ww;

    const int rsub = lane >> 3;        // 0..7
    const int cq = (lane & 7) * 4;     // 0,4,..,28
    const int dl = (lane < Dd) ? lane : (Dd - 1);
    const int gw = lane & 31;          // g column held by this lane

    float4 pre[6];
    float gcur[5], gnxt[5];

    // prologue: first tile of x -> LDS, g -> regs
    {
        const int t = REV ? (NT - 1) : 0;
        const int w0 = t * TW;
#pragma unroll
        for (int i = 0; i < 6; ++i) {
            const int dd = i * 8 + rsub;
            pre[i] = *reinterpret_cast<const float4*>(xrow + (size_t)dd * HW + (w0 + cq));
        }
#pragma unroll
        for (int k = 0; k < 5; ++k) gcur[k] = grow[(size_t)k * HW + (w0 + gw)];
#pragma unroll
        for (int i = 0; i < 6; ++i) {
            const int dd = i * 8 + rsub;
            xs[dd][cq + 0] = pre[i].x;
            xs[dd][cq + 1] = pre[i].y;
            xs[dd][cq + 2] = pre[i].z;
            xs[dd][cq + 3] = pre[i].w;
        }
    }

    float A = NEGBIG;

    for (int tt = 0; tt < NT; ++tt) {
        const int t = REV ? (NT - 1 - tt) : tt;
        const int w0 = t * TW;

        // issue next-tile loads early (hidden under the 32-step chain)
        if (tt + 1 < NT) {
            const int tn = REV ? (NT - 2 - tt) : (tt + 1);
            const int wn = tn * TW;
#pragma unroll
            for (int i = 0; i < 6; ++i) {
                const int dd = i * 8 + rsub;
                pre[i] = *reinterpret_cast<const float4*>(xrow + (size_t)dd * HW + (wn + cq));
            }
#pragma unroll
            for (int k = 0; k < 5; ++k) gnxt[k] = grow[(size_t)k * HW + (wn + gw)];
        }
        float4 opre[6];
        if (COMB) {
#pragma unroll
            for (int i = 0; i < 6; ++i) {
                const int dd = i * 8 + rsub;
                opre[i] = *reinterpret_cast<const float4*>(orow + (size_t)dd * HW + (w0 + cq));
            }
        }

        // 32 recurrence steps; g via readlane (no memory on critical path)
#pragma unroll 8
        for (int wk = 0; wk < TW; ++wk) {
            const int col = REV ? (TW - 1 - wk) : wk;
            const float g0v = rdlane(gcur[0], col);
            const float g1v = rdlane(gcur[1], col);
            const float g2v = rdlane(gcur[2], col);
            const float g3v = rdlane(gcur[3], col);
            const float g4v = rdlane(gcur[4], col);
            const float cs = xs[dl][col];
            A = sga_step(A, cs, g0v, g1v, g2v, g3v, g4v, lane, (tt == 0 && wk == 0));
            if (lane < Dd) os[lane][col] = A;
        }

        // commit next tile (single wave: in-order, no barrier needed)
        if (tt + 1 < NT) {
#pragma unroll
            for (int i = 0; i < 6; ++i) {
                const int dd = i * 8 + rsub;
                xs[dd][cq + 0] = pre[i].x;
                xs[dd][cq + 1] = pre[i].y;
                xs[dd][cq + 2] = pre[i].z;
                xs[dd][cq + 3] = pre[i].w;
            }
#pragma unroll
            for (int k = 0; k < 5; ++k) gcur[k] = gnxt[k];
        }

        // flush os tile (coalesced float4), combining if requested
#pragma unroll
        for (int i = 0; i < 6; ++i) {
            const int dd = i * 8 + rsub;
            float4 v;
            v.x = os[dd][cq + 0];
            v.y = os[dd][cq + 1];
            v.z = os[dd][cq + 2];
            v.w = os[dd][cq + 3];
            if (COMB) {
                v.x = fmaxf(v.x, opre[i].x);
                v.y = fmaxf(v.y, opre[i].y);
                v.z = fmaxf(v.z, opre[i].z);
                v.w = fmaxf(v.w, opre[i].w);
            }
            *reinterpret_cast<float4*>(orow + (size_t)dd * HW + (w0 + cq)) = v;
        }
    }
}

// ---- H-direction scan (axis=3). Block = 16 columns, 8 waves (2 cols/wave).
// Period = KH=4 h-rows per barrier. x/out in 64B chunks; g staged in LDS;
// LDS stride padded to 17 (conflict-free stride-17 reads).
template <bool REV>
__global__ __launch_bounds__(512) void sga_h(const float* __restrict__ x,
                                             const float* __restrict__ g,
                                             float* __restrict__ out) {
    constexpr int WT = 16;
    constexpr int KH = 4;
    constexpr int NPER = Hh / KH;      // 24
    constexpr int NWB = Ww / WT;       // 12

    __shared__ float xs[2][KH][Dd][WT + 1];
    __shared__ float os[2][KH][Dd][WT + 1];
    __shared__ __align__(16) float gs[2][KH][WT][8];

    const int c = blockIdx.x / NWB;
    const int w0 = (blockIdx.x - c * NWB) * WT;
    const int tid = threadIdx.x;
    const int lane = tid & 63;
    const int wv = tid >> 6;          // 0..7
    const int c0 = wv * 2, c1 = wv * 2 + 1;
    const size_t HW = (size_t)Hh * Ww;

    const float* xb = x + (size_t)c * Dd * HW;
    const float* gb = g + (size_t)c * 5 * HW;
    float* ob = out + (size_t)c * Dd * HW;

    const int dl = (lane < Dd) ? lane : (Dd - 1);

    // staging decomposition: idx = tid + i*512 over [KH][Dd][WT]
    int hp_[6], osoff_[6];
    size_t goff_[6];
#pragma unroll
    for (int i = 0; i < 6; ++i) {
        const int idx = tid + i * 512;
        const int hp = idx / (Dd * WT);
        const int d = (idx - hp * Dd * WT) / WT;
        const int w = idx & (WT - 1);
        hp_[i] = hp;
        osoff_[i] = (hp * Dd + d) * (WT + 1) + w;
        goff_[i] = (size_t)d * HW + (w0 + w);
    }
    // g staging mapping (tid < 320)
    const int gk = tid / 64;
    const int ghp = (tid & 63) / WT;
    const int gw = tid & (WT - 1);
    const bool gstage = tid < 5 * 64;

    float xr[6], gr = 0.f, onow[6], oprev[6];

    // prologue: stage period 0
    {
#pragma unroll
        for (int i = 0; i < 6; ++i) {
            const int h = REV ? (Hh - 1 - hp_[i]) : hp_[i];
            xr[i] = xb[goff_[i] + (size_t)h * Ww];
        }
        if (gstage) {
            const int h = REV ? (Hh - 1 - ghp) : ghp;
            gr = gb[(size_t)gk * HW + (size_t)h * Ww + (w0 + gw)];
        }
#pragma unroll
        for (int i = 0; i < 6; ++i) xs[0][0][0][osoff_[i]] = xr[i];
        if (gstage) gs[0][ghp][gw][gk] = gr;
    }
    __syncthreads();

    float A0 = NEGBIG, A1 = NEGBIG;

    for (int per = 0; per < NPER; ++per) {
        const int buf = per & 1;

        // (1) issue global loads: x,g for period per+1; out-RMW values for per
        if (per + 1 < NPER) {
#pragma unroll
            for (int i = 0; i < 6; ++i) {
                const int p = (per + 1) * KH + hp_[i];
                const int h = REV ? (Hh - 1 - p) : p;
                xr[i] = xb[goff_[i] + (size_t)h * Ww];
            }
            if (gstage) {
                const int p = (per + 1) * KH + ghp;
                const int h = REV ? (Hh - 1 - p) : p;
                gr = gb[(size_t)gk * HW + (size_t)h * Ww + (w0 + gw)];
            }
        }
#pragma unroll
        for (int i = 0; i < 6; ++i) {
            const int p = per * KH + hp_[i];
            const int h = REV ? (Hh - 1 - p) : p;
            onow[i] = ob[goff_[i] + (size_t)h * Ww];
        }

        // (2) compute KH steps (2 independent columns per wave for ILP)
#pragma unroll
        for (int hp = 0; hp < KH; ++hp) {
            const int p = per * KH + hp;
            const float cs0 = xs[buf][hp][dl][c0];
            const float cs1 = xs[buf][hp][dl][c1];
            const float4 ga = *reinterpret_cast<const float4*>(&gs[buf][hp][c0][0]);
            const float ga4 = gs[buf][hp][c0][4];
            const float4 gc = *reinterpret_cast<const float4*>(&gs[buf][hp][c1][0]);
            const float gc4 = gs[buf][hp][c1][4];
            A0 = sga_step(A0, cs0, ga.x, ga.y, ga.z, ga.w, ga4, lane, p == 0);
            A1 = sga_step(A1, cs1, gc.x, gc.y, gc.z, gc.w, gc4, lane, p == 0);
            if (lane < Dd) {
                os[buf][hp][lane][c0] = A0;
                os[buf][hp][lane][c1] = A1;
            }
        }

        // (3) flush period per-1 (combined with out values prefetched then)
        if (per > 0) {
#pragma unroll
            for (int i = 0; i < 6; ++i) {
                const int p = (per - 1) * KH + hp_[i];
                const int h = REV ? (Hh - 1 - p) : p;
                const float v = fmaxf(os[buf ^ 1][0][0][osoff_[i]], oprev[i]);
                ob[goff_[i] + (size_t)h * Ww] = v;
            }
        }
#pragma unroll
        for (int i = 0; i < 6; ++i) oprev[i] = onow[i];

        // (4) commit staged regs for period per+1
        if (per + 1 < NPER) {
#pragma unroll
            for (int i = 0; i < 6; ++i) xs[buf ^ 1][0][0][osoff_[i]] = xr[i];
            if (gstage) gs[buf ^ 1][ghp][gw][gk] = gr;
        }
        __syncthreads();
    }

    // epilogue: flush last period
    {
        const int per = NPER - 1;
        const int buf = per & 1;
#pragma unroll
        for (int i = 0; i < 6; ++i) {
            const int p = per * KH + hp_[i];
            const int h = REV ? (Hh - 1 - p) : p;
            const float v = fmaxf(os[buf][0][0][osoff_[i]], oprev[i]);
            ob[goff_[i] + (size_t)h * Ww] = v;
        }
    }
}

extern "C" void kernel_launch(void* const* d_in, const int* in_sizes, int n_in,
                              void* d_out, int out_size, void* d_ws, size_t ws_size,
                              hipStream_t stream) {
    const float* x  = (const float*)d_in[0];
    const float* g0 = (const float*)d_in[1];
    const float* g1 = (const float*)d_in[2];
    const float* g2 = (const float*)d_in[3];
    const float* g3 = (const float*)d_in[4];
    float* out = (float*)d_out;

    sga_w<false, false><<<Cc * Hh, 64, 0, stream>>>(x, g0, out);
    sga_w<true,  true ><<<Cc * Hh, 64, 0, stream>>>(x, g1, out);
    sga_h<false><<<Cc * (Ww / 16), 512, 0, stream>>>(x, g2, out);
    sga_h<true ><<<Cc * (Ww / 16), 512, 0, stream>>>(x, g3, out);
}